// Round 18
// baseline (805.736 us; speedup 1.0000x reference)
//
#include <hip/hip_runtime.h>
#include <math.h>

typedef float fx4 __attribute__((ext_vector_type(4)));
typedef _Float16 hx8 __attribute__((ext_vector_type(8)));
typedef _Float16 hx4 __attribute__((ext_vector_type(4)));

#define GL16(g, l) __builtin_amdgcn_global_load_lds( \
    (const __attribute__((address_space(1))) void*)(g), \
    (__attribute__((address_space(3))) void*)(l), 16, 0, 0)

// ---------------------------------------------------------------- fp32 -> fp16 cvt (grid-stride)
template<bool NT>
__global__ __launch_bounds__(256)
void cvt16(const float* __restrict__ in, _Float16* __restrict__ outh, int n8)
{
  for (int i = blockIdx.x * 256 + threadIdx.x; i < n8; i += gridDim.x * 256){
    fx4 a, b;
    if (NT){
      a = __builtin_nontemporal_load((const fx4*)(in + (size_t)i * 8));
      b = __builtin_nontemporal_load((const fx4*)(in + (size_t)i * 8 + 4));
    } else {
      a = *(const fx4*)(in + (size_t)i * 8);
      b = *(const fx4*)(in + (size_t)i * 8 + 4);
    }
    hx8 h;
    #pragma unroll
    for (int e = 0; e < 4; e++){ h[e] = (_Float16)a[e]; h[4+e] = (_Float16)b[e]; }
    if (NT) __builtin_nontemporal_store(h, (hx8*)(outh + (size_t)i * 8));
    else    *(hx8*)(outh + (size_t)i * 8) = h;
  }
}

// ---------------------------------------------------------------- embed gather + gk/beta fused (one block per t)
__global__ __launch_bounds__(256)
void embed_gkb(const int* __restrict__ ids, const float* __restrict__ emb,
               const float* __restrict__ Wgk, const float* __restrict__ Wb,
               const float* __restrict__ b_b, const float* __restrict__ A_log,
               const float* __restrict__ dtb, float* __restrict__ x,
               _Float16* __restrict__ xh, float* __restrict__ gko,
               float* __restrict__ beto)
{
  int t = blockIdx.x, tid = threadIdx.x, lane = tid & 63, w = tid >> 6;
  __shared__ __align__(16) float xs[1024];
  __shared__ float res[24];
  int id = ids[t];
  fx4 v = *(const fx4*)(emb + (size_t)id * 1024 + tid * 4);
  *(fx4*)&xs[tid * 4] = v;
  *(fx4*)(x + (size_t)t * 1024 + tid * 4) = v;
  hx4 h;
  #pragma unroll
  for (int e = 0; e < 4; e++) h[e] = (_Float16)v[e];
  *(hx4*)(xh + (size_t)t * 1024 + tid * 4) = h;
  __syncthreads();
  for (int r = w; r < 24; r += 4){
    const float* wrow = (r < 12) ? (Wgk + r * 1024) : (Wb + (r - 12) * 1024);
    float a = 0.f;
    #pragma unroll
    for (int j = 0; j < 16; j++) a += xs[lane + j * 64] * wrow[lane + j * 64];
    #pragma unroll
    for (int d = 1; d < 64; d <<= 1) a += __shfl_xor(a, d, 64);
    if (lane == 0) res[r] = a;
  }
  __syncthreads();
  if (tid < 12){
    float z = res[tid] + dtb[tid];
    float sp = (z > 20.f) ? z : log1pf(expf(z));
    gko [(size_t)t * 12 + tid] = -expf(A_log[tid]) * sp;
    float b = res[12 + tid] + b_b[tid];
    beto[(size_t)t * 12 + tid] = 1.f / (1.f + expf(-b));
  }
}

// ---------------------------------------------------------------- fp16 GEMM, counted-vmcnt 2-deep pipeline (R14)
// NTC: LDS-staged coalesced epilogue + nontemporal full-sector C stores.
template<int MT, int NT, int WR, int WC, bool OUT16, bool NTC>
__global__ __launch_bounds__(WR*WC*64, 2)
void gemm_hh(const _Float16* __restrict__ A, const _Float16* __restrict__ B,
             void* __restrict__ Cv, const float* __restrict__ bias,
             int M, int N, int K)
{
  constexpr int BM = WR*MT*16, BN = WC*NT*16;
  constexpr int T  = WR*WC*64;
  constexpr int ABYTES = BM*128, BUF = ABYTES + BN*128;
  constexpr int FA = BM*8/T, FB = BN*8/T;
  static_assert(FA + FB == 4, "vmcnt literal assumes 4 loads/thread/tile");
  __shared__ __align__(16) char smem[2*BUF];

  const int tid = threadIdx.x;
  const int lane = tid & 63, w = tid >> 6;
  const int wr = w / WC, wc = w % WC;
  const int lm = lane & 15, lg = lane >> 4;
  const int nk = K >> 6;

  const int nwgx = gridDim.x, nwg = nwgx * gridDim.y;
  int orig = blockIdx.y * nwgx + blockIdx.x;
  int logical = (orig & 7) * (nwg >> 3) + (orig >> 3);   // nwg % 8 == 0 in all uses
  const int m0 = (logical % nwgx) * BM, n0 = (logical / nwgx) * BN;

  const char* gsA[FA];
  const char* gsB[FB];
  int fdA[FA], fdB[FB];
  #pragma unroll
  for (int j = 0; j < FA; j++){
    int f = tid + j*T;
    int row = f >> 3, oct = (f & 7) ^ (row & 7);
    gsA[j] = (const char*)(A + (size_t)(m0 + row) * K + oct * 8);
    fdA[j] = f * 16;
  }
  #pragma unroll
  for (int j = 0; j < FB; j++){
    int f = tid + j*T;
    int row = f >> 3, oct = (f & 7) ^ (row & 7);
    int rb = n0 + row; if (rb > N - 1) rb = N - 1;
    gsB[j] = (const char*)(B + (size_t)rb * K + oct * 8);
    fdB[j] = ABYTES + f * 16;
  }

  fx4 acc[MT][NT];
  #pragma unroll
  for (int mt = 0; mt < MT; mt++)
    #pragma unroll
    for (int nt = 0; nt < NT; nt++)
      acc[mt][nt] = (fx4){0.f, 0.f, 0.f, 0.f};

  #pragma unroll
  for (int j = 0; j < FA; j++) GL16(gsA[j], smem + fdA[j]);
  #pragma unroll
  for (int j = 0; j < FB; j++) GL16(gsB[j], smem + fdB[j]);
  if (nk > 1){
    #pragma unroll
    for (int j = 0; j < FA; j++) GL16(gsA[j] + 128, smem + BUF + fdA[j]);
    #pragma unroll
    for (int j = 0; j < FB; j++) GL16(gsB[j] + 128, smem + BUF + fdB[j]);
  }

  for (int kt = 0; kt < nk; kt++){
    if (kt + 1 < nk) asm volatile("s_waitcnt vmcnt(4)" ::: "memory");
    else             asm volatile("s_waitcnt vmcnt(0)" ::: "memory");
    asm volatile("s_barrier" ::: "memory");        // tile kt landed, block-wide

    const char* bp = smem + (kt & 1) * BUF;
    #pragma unroll
    for (int s = 0; s < 2; s++){
      hx8 af[MT], bfr[NT];
      #pragma unroll
      for (int mt = 0; mt < MT; mt++){
        int row = wr*MT*16 + mt*16 + lm;
        af[mt] = *(const hx8*)(bp + row*128 + (((s*4 + lg) ^ (row & 7)) << 4));
      }
      #pragma unroll
      for (int nt = 0; nt < NT; nt++){
        int row = wc*NT*16 + nt*16 + lm;
        bfr[nt] = *(const hx8*)(bp + ABYTES + row*128 + (((s*4 + lg) ^ (row & 7)) << 4));
      }
      #pragma unroll
      for (int mt = 0; mt < MT; mt++)
        #pragma unroll
        for (int nt = 0; nt < NT; nt++)
          acc[mt][nt] = __builtin_amdgcn_mfma_f32_16x16x32_f16(af[mt], bfr[nt], acc[mt][nt], 0, 0, 0);
    }
    asm volatile("s_barrier" ::: "memory");        // all reads of buf[kt&1] done

    if (kt + 2 < nk){                              // restage the buffer just read
      char* nb = smem + (kt & 1) * BUF;
      size_t ko = (size_t)(kt + 2) * 128;
      #pragma unroll
      for (int j = 0; j < FA; j++) GL16(gsA[j] + ko, nb + fdA[j]);
      #pragma unroll
      for (int j = 0; j < FB; j++) GL16(gsB[j] + ko, nb + fdB[j]);
    }
  }

  if (NTC && !OUT16){
    // LDS-staged coalesced epilogue (two 64-row halves, stride-132 pad).
    float* C = (float*)Cv;
    float* eb = (float*)smem;                      // 64x132 fp32 = 33.8KB
    #pragma unroll
    for (int hh = 0; hh < 2; hh++){
      asm volatile("s_barrier" ::: "memory");      // smem free (K-loop / prev half done)
      if (wr == hh){
        #pragma unroll
        for (int mt = 0; mt < MT; mt++)
          #pragma unroll
          for (int nt = 0; nt < NT; nt++){
            int lrow = mt*16 + (lg << 2);
            int col = wc*NT*16 + nt*16 + lm;
            #pragma unroll
            for (int j = 0; j < 4; j++)
              eb[(lrow + j)*132 + col] = acc[mt][nt][j];
          }
      }
      asm volatile("s_barrier" ::: "memory");
      #pragma unroll
      for (int k = 0; k < 64*BN/(4*T); k++){
        int idx = tid + k*T;
        int lrow = idx / (BN/4), colv = (idx % (BN/4)) * 4;
        int grow = m0 + hh*64 + lrow;
        int gcol = n0 + colv;
        fx4 vv = *(const fx4*)&eb[lrow*132 + colv];
        if (gcol + 3 < N){
          if (bias){
            fx4 b4 = *(const fx4*)&bias[gcol];
            #pragma unroll
            for (int j = 0; j < 4; j++) vv[j] += b4[j];
          }
          __builtin_nontemporal_store(vv, (fx4*)&C[(size_t)grow * N + gcol]);
        } else {
          #pragma unroll
          for (int j = 0; j < 4; j++)
            if (gcol + j < N)
              C[(size_t)grow * N + gcol + j] = vv[j] + (bias ? bias[gcol + j] : 0.f);
        }
      }
    }
  } else if (OUT16){
    _Float16* Ch = (_Float16*)Cv;
    #pragma unroll
    for (int nt = 0; nt < NT; nt++){
      int col = n0 + wc*NT*16 + nt*16 + lm;
      if (col < N){
        #pragma unroll
        for (int mt = 0; mt < MT; mt++){
          int r0 = m0 + wr*MT*16 + mt*16 + (lg << 2);
          #pragma unroll
          for (int j = 0; j < 4; j++)
            Ch[(size_t)(r0 + j) * N + col] = (_Float16)acc[mt][nt][j];
        }
      }
    }
  } else {
    float* C = (float*)Cv;
    #pragma unroll
    for (int nt = 0; nt < NT; nt++){
      int col = n0 + wc*NT*16 + nt*16 + lm;
      if (col < N){
        float bsv = bias ? bias[col] : 0.f;
        #pragma unroll
        for (int mt = 0; mt < MT; mt++){
          int r0 = m0 + wr*MT*16 + mt*16 + (lg << 2);
          #pragma unroll
          for (int j = 0; j < 4; j++)
            C[(size_t)(r0 + j) * N + col] = acc[mt][nt][j] + bsv;
        }
      }
    }
  }
}

// ---------------------------------------------------------------- fused conv+silu(+l2norm), all of q/k/v
__global__ __launch_bounds__(256)
void conv_fused(const float* __restrict__ qkvg, const float* __restrict__ wqc,
                const float* __restrict__ wkc, const float* __restrict__ wvc,
                float* __restrict__ qpp, float* __restrict__ kpp,
                float* __restrict__ vpp)
{
  int traw = blockIdx.x;
  int t = (traw & 7) * 256 + (traw >> 3);       // 2048 % 8 == 0, bijective
  int gc = blockIdx.y * 256 + threadIdx.x;      // 0..3071 (wave = one 64-ch head)
  const float* cw; int cc;
  if (gc < 768){ cw = wqc; cc = gc; }
  else if (gc < 1536){ cw = wkc; cc = gc - 768; }
  else { cw = wvc; cc = gc - 1536; }
  float y = 0.f;
  #pragma unroll
  for (int i = 0; i < 4; i++){
    int ts = t - 3 + i;
    if (ts >= 0) y += cw[cc * 4 + i] * qkvg[(size_t)ts * 4608 + gc];
  }
  y = y / (1.f + expf(-y));                     // silu
  if (gc < 1536){                               // l2norm over head (wave-aligned)
    float ss = y * y;
    #pragma unroll
    for (int d = 1; d < 64; d <<= 1) ss += __shfl_xor(ss, d, 64);
    y *= rsqrtf(ss + 1e-6f) * (gc < 768 ? 0.125f : 1.0f);
  }
  if (gc < 768)       qpp[(size_t)t * 768 + gc] = y;
  else if (gc < 1536) kpp[(size_t)t * 768 + gc - 768] = y;
  else                vpp[(size_t)t * 1536 + gc - 1536] = y;
}

// ---------------------------------------------------------------- phase A: per-(head,chunk) WY factors
__global__ __launch_bounds__(256)
void phaseA(const float* __restrict__ qp, const float* __restrict__ kp,
            const float* __restrict__ vp, const float* __restrict__ gkv,
            const float* __restrict__ bev, float* __restrict__ Wt,
            float* __restrict__ Uvv, float* __restrict__ Mg,
            float* __restrict__ Ng, float* __restrict__ Ca,
            float* __restrict__ bv)
{
  const int braw = blockIdx.x;
  const int blk = (braw & 7) * 48 + (braw >> 3);   // 384 % 8 == 0, bijective
  const int h = blk % 12, c = blk / 12, t0 = c * 64;
  const int tid = threadIdx.x;

  __shared__ __align__(16) float Kc[4096];     // K chunk [64][64]
  __shared__ __align__(16) float X[12288];     // [64][192]: cols 0..127 Uv, 128..191 W
  __shared__ float Pp[2016];                   // packed strict-lower P
  __shared__ float gt[64], bb[64], be[64], eg[64];
  __shared__ float Gtot;

  { // load K chunk
    int i = tid >> 2, q4 = tid & 3;
    const float* src = kp + (size_t)(t0 + i) * 768 + h * 64 + q4 * 16;
    #pragma unroll
    for (int e = 0; e < 4; e++)
      *(fx4*)&Kc[i * 64 + q4 * 16 + e * 4] = *(const fx4*)(src + e * 4);
  }
  if (tid < 64){ // within-chunk cumulative log-decay
    float g = gkv[(size_t)(t0 + tid) * 12 + h];
    #pragma unroll
    for (int d = 1; d < 64; d <<= 1){
      float ts = __shfl_up(g, d, 64);
      if (tid >= d) g += ts;
    }
    gt[tid] = g;
    bb[tid] = expf(g);
    be[tid] = bev[(size_t)(t0 + tid) * 12 + h];
    if (tid == 63) Gtot = g;
  }
  __syncthreads();
  const float GT = Gtot;
  if (tid < 64) eg[tid] = expf(GT - gt[tid]);

  { // P_ij = beta_i * (k_i.k_j) * exp(gt_i - gt_j), j < i
    int i = tid >> 2, jb = tid & 3;
    float ki[64];
    #pragma unroll
    for (int d = 0; d < 64; d++) ki[d] = Kc[i * 64 + d];
    float gi = gt[i], bei = be[i];
    int pbase = (i * (i - 1)) >> 1;
    for (int jj = 0; jj < 16; jj++){
      int j = jb * 16 + jj;
      if (j < i){
        float dot = 0.f;
        #pragma unroll
        for (int d = 0; d < 64; d++) dot += ki[d] * Kc[j * 64 + d];
        Pp[pbase + j] = bei * dot * expf(gi - gt[j]);
      }
    }
  }
  { // X init = diag(beta)[V | diag(b)K]
    int i = tid >> 2, seg = tid & 3;
    float bei = be[i], bbi = bb[i];
    #pragma unroll
    for (int u = 0; u < 12; u++){
      int colv = seg * 48 + u * 4;
      fx4 val;
      if (colv < 128){
        val = *(const fx4*)(vp + (size_t)(t0 + i) * 1536 + h * 128 + colv);
        #pragma unroll
        for (int e = 0; e < 4; e++) val[e] *= bei;
      } else {
        int d0 = colv - 128;
        #pragma unroll
        for (int e = 0; e < 4; e++) val[e] = bei * bbi * Kc[i * 64 + d0 + e];
      }
      *(fx4*)&X[i * 192 + colv] = val;
    }
  }
  __syncthreads();

  // forward substitution: X <- (I+P)^-1 X
  for (int i = 1; i < 64; i++){
    if (tid < 192){
      int pbase = (i * (i - 1)) >> 1;
      float accv = 0.f;
      for (int j = 0; j < i; j++) accv += Pp[pbase + j] * X[j * 192 + tid];
      X[i * 192 + tid] -= accv;
    }
    __syncthreads();
  }

  // store Uv, W
  for (int e = tid; e < 12288; e += 256){
    int i = e / 192, colv = e - i * 192;
    float xv = X[e];
    if (colv < 128) Uvv[(size_t)blk * 8192 + i * 128 + colv] = xv;
    else            Wt [(size_t)blk * 4096 + i * 64 + (colv - 128)] = xv;
  }

  { // M = exp(G) I - K'^T W
    int d2 = tid & 63, d1b = tid >> 6;
    for (int ii = 0; ii < 16; ii++){
      int d1 = d1b * 16 + ii;
      float s = 0.f;
      for (int j = 0; j < 64; j++)
        s += eg[j] * Kc[j * 64 + d1] * X[j * 192 + 128 + d2];
      Mg[(size_t)blk * 4096 + d1 * 64 + d2] = ((d1 == d2) ? expf(GT) : 0.f) - s;
    }
  }
  { // N = K'^T Uv
    int vv = tid & 127, d1b = tid >> 7;
    for (int ii = 0; ii < 32; ii++){
      int d1 = d1b * 32 + ii;
      float s = 0.f;
      for (int j = 0; j < 64; j++)
        s += eg[j] * Kc[j * 64 + d1] * X[j * 192 + vv];
      Ng[(size_t)blk * 8192 + d1 * 128 + vv] = s;
    }
  }
  { // Cattn_ij = (q_i.k_j) exp(gt_i-gt_j), j <= i
    int i = tid >> 2, jb = tid & 3;
    float qi[64];
    {
      const float* src = qp + (size_t)(t0 + i) * 768 + h * 64;
      #pragma unroll
      for (int q4 = 0; q4 < 16; q4++){
        fx4 t4 = *(const fx4*)(src + q4 * 4);
        #pragma unroll
        for (int e = 0; e < 4; e++) qi[q4 * 4 + e] = t4[e];
      }
    }
    float gi = gt[i];
    for (int jj = 0; jj < 16; jj++){
      int j = jb * 16 + jj;
      float outv = 0.f;
      if (j <= i){
        float dot = 0.f;
        #pragma unroll
        for (int d = 0; d < 64; d++) dot += qi[d] * Kc[j * 64 + d];
        outv = dot * expf(gi - gt[j]);
      }
      Ca[(size_t)blk * 4096 + i * 64 + j] = outv;
    }
  }
  if (tid < 64) bv[(size_t)blk * 64 + tid] = bb[tid];
}

// ---------------------------------------------------------------- phase B: sequential S <- M S + N
__global__ __launch_bounds__(256)
void phaseB(const float* __restrict__ Mg, const float* __restrict__ Ng,
            float* __restrict__ Sst)
{
  const int h = blockIdx.x >> 2, v0 = (blockIdx.x & 3) * 32;
  const int tid = threadIdx.x, lane = tid & 63, w = tid >> 6;
  const int lm = lane & 15, lg = lane >> 4;
  __shared__ __align__(16) float ST[2048];   // [kb 0..7][vv 0..31][r&7]

  #pragma unroll
  for (int e = 0; e < 2; e++)
    *(fx4*)&ST[(tid + e * 256) * 4] = (fx4){0.f,0.f,0.f,0.f};
  {
    float* dst = Sst + (size_t)h * 8192;     // S_states[0] slice = 0
    #pragma unroll
    for (int e = 0; e < 2; e++){
      int r = (tid >> 3) + e * 32;
      *(fx4*)(dst + (size_t)r * 128 + v0 + (tid & 7) * 4) = (fx4){0.f,0.f,0.f,0.f};
    }
  }
  __syncthreads();

  fx4 rm[2][2];
  float rn[2][4];
  auto loadMN = [&](int cc){
    const float* mb = Mg + ((size_t)cc * 12 + h) * 4096 + (w * 16 + lm) * 64 + lg * 8;
    rm[0][0] = *(const fx4*)(mb);
    rm[0][1] = *(const fx4*)(mb + 4);
    rm[1][0] = *(const fx4*)(mb + 32);
    rm[1][1] = *(const fx4*)(mb + 36);
    const float* nb = Ng + ((size_t)cc * 12 + h) * 8192 + v0;
    #pragma unroll
    for (int nt = 0; nt < 2; nt++)
      #pragma unroll
      for (int j = 0; j < 4; j++)
        rn[nt][j] = nb[(w * 16 + lg * 4 + j) * 128 + nt * 16 + lm];
  };
  loadMN(0);

  for (int c = 0; c < 32; c++){
    hx8 mf[2];
    #pragma unroll
    for (int s = 0; s < 2; s++)
      #pragma unroll
      for (int e = 0; e < 4; e++){
        mf[s][e]     = (_Float16)rm[s][0][e];
        mf[s][4 + e] = (_Float16)rm[s][1][e];
      }
    fx4 acc[2];
    #pragma unroll
    for (int nt = 0; nt < 2; nt++)
      #pragma unroll
      for (int j = 0; j < 4; j++) acc[nt][j] = rn[nt][j];
    if (c + 1 < 32) loadMN(c + 1);

    hx8 bfr[2][2];
    #pragma unroll
    for (int s = 0; s < 2; s++)
      #pragma unroll
      for (int nt = 0; nt < 2; nt++){
        int vv = nt * 16 + lm, kb = s * 4 + lg;
        fx4 p0 = *(const fx4*)&ST[kb * 256 + vv * 8];
        fx4 p1 = *(const fx4*)&ST[kb * 256 + vv * 8 + 4];
        #pragma unroll
        for (int e = 0; e < 4; e++){
          bfr[s][nt][e]     = (_Float16)p0[e];
          bfr[s][nt][4 + e] = (_Float16)p1[e];
        }
      }
    #pragma unroll
    for (int s = 0; s < 2; s++)
      #pragma unroll
      for (int nt = 0; nt < 2; nt++)
        acc[nt] = __builtin_amdgcn_mfma_f32_16x16x32_f16(mf[s], bfr[s][nt], acc[nt], 0, 0, 0);
    __syncthreads();   // all ST reads done
    float* dstS = (c + 1 < 32) ? (Sst + ((size_t)(c + 1) * 12 + h) * 8192 + v0) : nullptr;
    #pragma unroll
    for (int nt = 0; nt < 2; nt++){
      int vv = nt * 16 + lm;
      #pragma unroll
      for (int j = 0; j < 4; j++){
        int r = w * 16 + lg * 4 + j;
        ST[(r >> 3) * 256 + vv * 8 + (r & 7)] = acc[nt][j];
        if (dstS) dstS[(size_t)r * 128 + vv] = acc[nt][j];
      }
    }
    __syncthreads();
  }
}

// ---------------------------------------------------------------- phase C: chunk outputs + fused RMSNorm*silu-gate
__global__ __launch_bounds__(256)
void phaseC(const float* __restrict__ qp, const float* __restrict__ Sst,
            const float* __restrict__ Wt, const float* __restrict__ Uvv,
            const float* __restrict__ Ca, const float* __restrict__ bv,
            const float* __restrict__ qkvg, const float* __restrict__ gnw,
            _Float16* __restrict__ ogh)
{
  const int braw = blockIdx.x;
  const int blk = (braw & 7) * 48 + (braw >> 3);   // 384 % 8 == 0, bijective
  const int h = blk % 12, c = blk / 12, t0 = c * 64;
  const int tid = threadIdx.x;

  __shared__ __align__(16) float S0l[8192];        // S0, then reused for o
  __shared__ __align__(16) float Ul[8192];
  __shared__ __align__(16) float Wl[4096];
  __shared__ float bl[64];

  #pragma unroll
  for (int e = 0; e < 8; e++){
    int i4 = tid + e * 256;
    *(fx4*)&S0l[i4 * 4] = *(const fx4*)(Sst + (size_t)blk * 8192 + i4 * 4);
    *(fx4*)&Ul[i4 * 4]  = *(const fx4*)(Uvv + (size_t)blk * 8192 + i4 * 4);
  }
  #pragma unroll
  for (int e = 0; e < 4; e++){
    int i4 = tid + e * 256;
    *(fx4*)&Wl[i4 * 4] = *(const fx4*)(Wt + (size_t)blk * 4096 + i4 * 4);
  }
  if (tid < 64) bl[tid] = bv[(size_t)blk * 64 + tid];
  __syncthreads();

  const int v = tid & 127, rh = tid >> 7;
  float s0c[64];
  #pragma unroll
  for (int d = 0; d < 64; d++) s0c[d] = S0l[d * 128 + v];

  // U = Uv - W @ S0
  for (int j = rh * 32; j < rh * 32 + 32; j++){
    float accv = 0.f;
    #pragma unroll
    for (int d = 0; d < 64; d++) accv += Wl[j * 64 + d] * s0c[d];
    Ul[j * 128 + v] -= accv;
  }
  __syncthreads();
  #pragma unroll
  for (int e = 0; e < 4; e++){   // Cattn into Wl
    int i4 = tid + e * 256;
    *(fx4*)&Wl[i4 * 4] = *(const fx4*)(Ca + (size_t)blk * 4096 + i4 * 4);
  }
  __syncthreads();               // also: all S0l reads (s0c) complete block-wide

  // o_i = b_i * q_i S0 + sum_{j<=i} Cattn_ij U_j   -> into S0l (reused)
  for (int i = rh * 32; i < rh * 32 + 32; i++){
    const float* qi = qp + (size_t)(t0 + i) * 768 + h * 64;
    float aq = 0.f;
    #pragma unroll
    for (int d = 0; d < 64; d++) aq += qi[d] * s0c[d];
    float ao = 0.f;
    for (int j = 0; j <= i; j++) ao += Wl[i * 64 + j] * Ul[j * 128 + v];
    S0l[i * 128 + v] = bl[i] * aq + ao;
  }
  __syncthreads();

  // fused rmsnorm * g_norm_w * silu(g): 4 waves x 16 rows each
  const int w4 = tid >> 6, lane = tid & 63;
  for (int r = 0; r < 16; r++){
    int row = w4 * 16 + r;
    float o1 = S0l[row * 128 + lane], o2 = S0l[row * 128 + 64 + lane];
    float ss = o1 * o1 + o2 * o2;
    #pragma unroll
    for (int d = 1; d < 64; d <<= 1) ss += __shfl_xor(ss, d, 64);
    float rr = rsqrtf(ss * (1.f / 128.f) + 1e-5f);
    size_t gb = (size_t)(t0 + row) * 4608 + 3072 + h * 128;
    float g1 = qkvg[gb + lane], g2 = qkvg[gb + 64 + lane];
    size_t ob = (size_t)(t0 + row) * 1536 + h * 128;
    ogh[ob + lane]      = (_Float16)(o1 * rr * gnw[lane]      * (g1 / (1.f + expf(-g1))));
    ogh[ob + 64 + lane] = (_Float16)(o2 * rr * gnw[64 + lane] * (g2 / (1.f + expf(-g2))));
  }
}

// ---------------------------------------------------------------- launcher
extern "C" void kernel_launch(void* const* d_in, const int* in_sizes, int n_in,
                              void* d_out, int out_size, void* d_ws, size_t ws_size,
                              hipStream_t stream)
{
  const int*   ids   = (const int*)d_in[0];
  const float* emb   = (const float*)d_in[1];
  const float* Wq    = (const float*)d_in[2];
  const float* Wk    = (const float*)d_in[3];
  const float* Wv    = (const float*)d_in[4];
  const float* Wg    = (const float*)d_in[5];
  const float* wqc   = (const float*)d_in[6];
  const float* wkc   = (const float*)d_in[7];
  const float* wvc   = (const float*)d_in[8];
  const float* Wgk   = (const float*)d_in[9];
  const float* Wb    = (const float*)d_in[10];
  const float* b_b   = (const float*)d_in[11];
  const float* A_log = (const float*)d_in[12];
  const float* dtb   = (const float*)d_in[13];
  const float* gnw   = (const float*)d_in[14];
  const float* Wo    = (const float*)d_in[15];
  const float* Wlm   = (const float*)d_in[16];
  const float* b_lm  = (const float*)d_in[17];
  float* out = (float*)d_out;

  // d_out doubles as scratch for intermediates that die before the LM GEMM.
  float* x    = out;               // 2048x1024 fp32
  float* qkvg = out + 2097152;     // 2048x4608 fp32 [q|k|v|g]
  float* qpp  = out + 11534336;    // 2048x768
  float* kpp  = out + 13107200;    // 2048x768
  float* vpp  = out + 14680064;    // 2048x1536
  float* gkb  = out + 17825792;    // 2048x12
  float* bet  = out + 17850368;    // 2048x12
  float* Wt   = out + 17874944;    // 384x64x64
  float* Uvv  = out + 19447808;    // 384x64x128
  float* Mg   = out + 22593536;    // 384x64x64
  float* Ng   = out + 24166400;    // 384x64x128
  float* Ca   = out + 27312128;    // 384x64x64
  float* bvv  = out + 28884992;    // 384x64
  float* Sst  = out + 28909568;    // 384x64x128 (chunk-start states)
  _Float16* x_h  = (_Float16*)(out + 35201024);  // 2048x1024 fp16
  _Float16* og_h = (_Float16*)(out + 36300000);  // 2048x1536 fp16

  // ws layout: h_h | Wqkvg_h | Wo_h | Wlm_h (R5 confirmed ws_size >= 120MB)
  _Float16* h_h     = (_Float16*)d_ws;           // 2048x1024 (survives LM GEMM)
  _Float16* Wqkvg_h = h_h + 2097152;             // 4608x1024 [Wq;Wk;Wv;Wg]
  _Float16* Wo_h    = Wqkvg_h + 4718592;         // 1024x1536
  _Float16* Wlm_h   = Wo_h + 1572864;            // 50257x1024

  cvt16<false><<<384,  256, 0, stream>>>(Wq, Wqkvg_h,           98304);
  cvt16<false><<<384,  256, 0, stream>>>(Wk, Wqkvg_h +  786432, 98304);
  cvt16<false><<<768,  256, 0, stream>>>(Wv, Wqkvg_h + 1572864, 196608);
  cvt16<false><<<768,  256, 0, stream>>>(Wg, Wqkvg_h + 3145728, 196608);
  cvt16<false><<<768,  256, 0, stream>>>(Wo, Wo_h, 196608);
  cvt16<true ><<<2048, 256, 0, stream>>>(Wlm, Wlm_h, 6432896);   // grid-stride, NT both ways

  embed_gkb<<<2048, 256, 0, stream>>>(ids, emb, Wgk, Wb, b_b, A_log, dtb,
                                      x, x_h, gkb, bet);
  gemm_hh<4,2,2,4,false,false><<<dim3(16, 36), 512, 0, stream>>>(x_h, Wqkvg_h, qkvg, nullptr, 2048, 4608, 1024);
  conv_fused<<<dim3(2048, 12), 256, 0, stream>>>(qkvg, wqc, wkc, wvc, qpp, kpp, vpp);
  phaseA<<<384, 256, 0, stream>>>(qpp, kpp, vpp, gkb, bet, Wt, Uvv, Mg, Ng, Ca, bvv);
  phaseB<<<48, 256, 0, stream>>>(Mg, Ng, Sst);
  phaseC<<<384, 256, 0, stream>>>(qpp, Sst, Wt, Uvv, Ca, bvv, qkvg, gnw, og_h);
  gemm_hh<4,2,2,4,true,false><<<dim3(16, 8), 512, 0, stream>>>(og_h, Wo_h, h_h, nullptr, 2048, 1024, 1536);
  // LM head: counted-vmcnt pipeline + LDS-staged coalesced NT epilogue
  gemm_hh<4,2,2,4,false,true><<<dim3(16, 393), 512, 0, stream>>>(h_h, Wlm_h, out, b_lm, 2048, 50257, 1024);
}

// Round 19
// 743.349 us; speedup vs baseline: 1.0839x; 1.0839x over previous
//
#include <hip/hip_runtime.h>
#include <math.h>

typedef float fx4 __attribute__((ext_vector_type(4)));
typedef _Float16 hx8 __attribute__((ext_vector_type(8)));
typedef _Float16 hx4 __attribute__((ext_vector_type(4)));

#define GL16(g, l) __builtin_amdgcn_global_load_lds( \
    (const __attribute__((address_space(1))) void*)(g), \
    (__attribute__((address_space(3))) void*)(l), 16, 0, 0)

// ---------------------------------------------------------------- fp32 -> fp16 cvt (grid-stride)
template<bool NT>
__global__ __launch_bounds__(256)
void cvt16(const float* __restrict__ in, _Float16* __restrict__ outh, int n8)
{
  for (int i = blockIdx.x * 256 + threadIdx.x; i < n8; i += gridDim.x * 256){
    fx4 a, b;
    if (NT){
      a = __builtin_nontemporal_load((const fx4*)(in + (size_t)i * 8));
      b = __builtin_nontemporal_load((const fx4*)(in + (size_t)i * 8 + 4));
    } else {
      a = *(const fx4*)(in + (size_t)i * 8);
      b = *(const fx4*)(in + (size_t)i * 8 + 4);
    }
    hx8 h;
    #pragma unroll
    for (int e = 0; e < 4; e++){ h[e] = (_Float16)a[e]; h[4+e] = (_Float16)b[e]; }
    *(hx8*)(outh + (size_t)i * 8) = h;
  }
}

// ---------------------------------------------------------------- embed gather + gk/beta fused (one block per t)
__global__ __launch_bounds__(256)
void embed_gkb(const int* __restrict__ ids, const float* __restrict__ emb,
               const float* __restrict__ Wgk, const float* __restrict__ Wb,
               const float* __restrict__ b_b, const float* __restrict__ A_log,
               const float* __restrict__ dtb, float* __restrict__ x,
               _Float16* __restrict__ xh, float* __restrict__ gko,
               float* __restrict__ beto)
{
  int t = blockIdx.x, tid = threadIdx.x, lane = tid & 63, w = tid >> 6;
  __shared__ __align__(16) float xs[1024];
  __shared__ float res[24];
  int id = ids[t];
  fx4 v = *(const fx4*)(emb + (size_t)id * 1024 + tid * 4);
  *(fx4*)&xs[tid * 4] = v;
  *(fx4*)(x + (size_t)t * 1024 + tid * 4) = v;
  hx4 h;
  #pragma unroll
  for (int e = 0; e < 4; e++) h[e] = (_Float16)v[e];
  *(hx4*)(xh + (size_t)t * 1024 + tid * 4) = h;
  __syncthreads();
  for (int r = w; r < 24; r += 4){
    const float* wrow = (r < 12) ? (Wgk + r * 1024) : (Wb + (r - 12) * 1024);
    float a = 0.f;
    #pragma unroll
    for (int j = 0; j < 16; j++) a += xs[lane + j * 64] * wrow[lane + j * 64];
    #pragma unroll
    for (int d = 1; d < 64; d <<= 1) a += __shfl_xor(a, d, 64);
    if (lane == 0) res[r] = a;
  }
  __syncthreads();
  if (tid < 12){
    float z = res[tid] + dtb[tid];
    float sp = (z > 20.f) ? z : log1pf(expf(z));
    gko [(size_t)t * 12 + tid] = -expf(A_log[tid]) * sp;
    float b = res[12 + tid] + b_b[tid];
    beto[(size_t)t * 12 + tid] = 1.f / (1.f + expf(-b));
  }
}

// ---------------------------------------------------------------- fp16 GEMM, counted-vmcnt 2-deep pipeline (R14)
// NTC: LDS-staged coalesced epilogue + nontemporal full-sector C stores.
template<int MT, int NT, int WR, int WC, bool OUT16, bool NTC>
__global__ __launch_bounds__(WR*WC*64, 2)
void gemm_hh(const _Float16* __restrict__ A, const _Float16* __restrict__ B,
             void* __restrict__ Cv, const float* __restrict__ bias,
             int M, int N, int K)
{
  constexpr int BM = WR*MT*16, BN = WC*NT*16;
  constexpr int T  = WR*WC*64;
  constexpr int ABYTES = BM*128, BUF = ABYTES + BN*128;
  constexpr int FA = BM*8/T, FB = BN*8/T;
  static_assert(FA + FB == 4, "vmcnt literal assumes 4 loads/thread/tile");
  __shared__ __align__(16) char smem[2*BUF];

  const int tid = threadIdx.x;
  const int lane = tid & 63, w = tid >> 6;
  const int wr = w / WC, wc = w % WC;
  const int lm = lane & 15, lg = lane >> 4;
  const int nk = K >> 6;

  const int nwgx = gridDim.x, nwg = nwgx * gridDim.y;
  int orig = blockIdx.y * nwgx + blockIdx.x;
  int logical = (orig & 7) * (nwg >> 3) + (orig >> 3);   // nwg % 8 == 0 in all uses
  const int m0 = (logical % nwgx) * BM, n0 = (logical / nwgx) * BN;

  const char* gsA[FA];
  const char* gsB[FB];
  int fdA[FA], fdB[FB];
  #pragma unroll
  for (int j = 0; j < FA; j++){
    int f = tid + j*T;
    int row = f >> 3, oct = (f & 7) ^ (row & 7);
    gsA[j] = (const char*)(A + (size_t)(m0 + row) * K + oct * 8);
    fdA[j] = f * 16;
  }
  #pragma unroll
  for (int j = 0; j < FB; j++){
    int f = tid + j*T;
    int row = f >> 3, oct = (f & 7) ^ (row & 7);
    int rb = n0 + row; if (rb > N - 1) rb = N - 1;
    gsB[j] = (const char*)(B + (size_t)rb * K + oct * 8);
    fdB[j] = ABYTES + f * 16;
  }

  fx4 acc[MT][NT];
  #pragma unroll
  for (int mt = 0; mt < MT; mt++)
    #pragma unroll
    for (int nt = 0; nt < NT; nt++)
      acc[mt][nt] = (fx4){0.f, 0.f, 0.f, 0.f};

  #pragma unroll
  for (int j = 0; j < FA; j++) GL16(gsA[j], smem + fdA[j]);
  #pragma unroll
  for (int j = 0; j < FB; j++) GL16(gsB[j], smem + fdB[j]);
  if (nk > 1){
    #pragma unroll
    for (int j = 0; j < FA; j++) GL16(gsA[j] + 128, smem + BUF + fdA[j]);
    #pragma unroll
    for (int j = 0; j < FB; j++) GL16(gsB[j] + 128, smem + BUF + fdB[j]);
  }

  for (int kt = 0; kt < nk; kt++){
    if (kt + 1 < nk) asm volatile("s_waitcnt vmcnt(4)" ::: "memory");
    else             asm volatile("s_waitcnt vmcnt(0)" ::: "memory");
    asm volatile("s_barrier" ::: "memory");        // tile kt landed, block-wide

    const char* bp = smem + (kt & 1) * BUF;
    #pragma unroll
    for (int s = 0; s < 2; s++){
      hx8 af[MT], bfr[NT];
      #pragma unroll
      for (int mt = 0; mt < MT; mt++){
        int row = wr*MT*16 + mt*16 + lm;
        af[mt] = *(const hx8*)(bp + row*128 + (((s*4 + lg) ^ (row & 7)) << 4));
      }
      #pragma unroll
      for (int nt = 0; nt < NT; nt++){
        int row = wc*NT*16 + nt*16 + lm;
        bfr[nt] = *(const hx8*)(bp + ABYTES + row*128 + (((s*4 + lg) ^ (row & 7)) << 4));
      }
      #pragma unroll
      for (int mt = 0; mt < MT; mt++)
        #pragma unroll
        for (int nt = 0; nt < NT; nt++)
          acc[mt][nt] = __builtin_amdgcn_mfma_f32_16x16x32_f16(af[mt], bfr[nt], acc[mt][nt], 0, 0, 0);
    }
    asm volatile("s_barrier" ::: "memory");        // all reads of buf[kt&1] done

    if (kt + 2 < nk){                              // restage the buffer just read
      char* nb = smem + (kt & 1) * BUF;
      size_t ko = (size_t)(kt + 2) * 128;
      #pragma unroll
      for (int j = 0; j < FA; j++) GL16(gsA[j] + ko, nb + fdA[j]);
      #pragma unroll
      for (int j = 0; j < FB; j++) GL16(gsB[j] + ko, nb + fdB[j]);
    }
  }

  if (NTC && !OUT16){
    // LDS-staged coalesced epilogue (two 64-row halves, stride-132 pad).
    float* C = (float*)Cv;
    float* eb = (float*)smem;                      // 64x132 fp32 = 33.8KB
    #pragma unroll
    for (int hh = 0; hh < 2; hh++){
      asm volatile("s_barrier" ::: "memory");      // smem free (K-loop / prev half done)
      if (wr == hh){
        #pragma unroll
        for (int mt = 0; mt < MT; mt++)
          #pragma unroll
          for (int nt = 0; nt < NT; nt++){
            int lrow = mt*16 + (lg << 2);
            int col = wc*NT*16 + nt*16 + lm;
            #pragma unroll
            for (int j = 0; j < 4; j++)
              eb[(lrow + j)*132 + col] = acc[mt][nt][j];
          }
      }
      asm volatile("s_barrier" ::: "memory");
      #pragma unroll
      for (int k = 0; k < 64*BN/(4*T); k++){
        int idx = tid + k*T;
        int lrow = idx / (BN/4), colv = (idx % (BN/4)) * 4;
        int grow = m0 + hh*64 + lrow;
        int gcol = n0 + colv;
        fx4 vv = *(const fx4*)&eb[lrow*132 + colv];
        if (gcol + 3 < N){
          if (bias){
            fx4 b4 = *(const fx4*)&bias[gcol];
            #pragma unroll
            for (int j = 0; j < 4; j++) vv[j] += b4[j];
          }
          __builtin_nontemporal_store(vv, (fx4*)&C[(size_t)grow * N + gcol]);
        } else {
          #pragma unroll
          for (int j = 0; j < 4; j++)
            if (gcol + j < N)
              C[(size_t)grow * N + gcol + j] = vv[j] + (bias ? bias[gcol + j] : 0.f);
        }
      }
    }
  } else if (OUT16){
    _Float16* Ch = (_Float16*)Cv;
    #pragma unroll
    for (int nt = 0; nt < NT; nt++){
      int col = n0 + wc*NT*16 + nt*16 + lm;
      if (col < N){
        #pragma unroll
        for (int mt = 0; mt < MT; mt++){
          int r0 = m0 + wr*MT*16 + mt*16 + (lg << 2);
          #pragma unroll
          for (int j = 0; j < 4; j++)
            Ch[(size_t)(r0 + j) * N + col] = (_Float16)acc[mt][nt][j];
        }
      }
    }
  } else {
    float* C = (float*)Cv;
    #pragma unroll
    for (int nt = 0; nt < NT; nt++){
      int col = n0 + wc*NT*16 + nt*16 + lm;
      if (col < N){
        float bsv = bias ? bias[col] : 0.f;
        #pragma unroll
        for (int mt = 0; mt < MT; mt++){
          int r0 = m0 + wr*MT*16 + mt*16 + (lg << 2);
          #pragma unroll
          for (int j = 0; j < 4; j++)
            C[(size_t)(r0 + j) * N + col] = acc[mt][nt][j] + bsv;
        }
      }
    }
  }
}

// ---------------------------------------------------------------- fused conv+silu(+l2norm), all of q/k/v
__global__ __launch_bounds__(256)
void conv_fused(const float* __restrict__ qkvg, const float* __restrict__ wqc,
                const float* __restrict__ wkc, const float* __restrict__ wvc,
                float* __restrict__ qpp, float* __restrict__ kpp,
                float* __restrict__ vpp)
{
  int traw = blockIdx.x;
  int t = (traw & 7) * 256 + (traw >> 3);       // 2048 % 8 == 0, bijective
  int gc = blockIdx.y * 256 + threadIdx.x;      // 0..3071 (wave = one 64-ch head)
  const float* cw; int cc;
  if (gc < 768){ cw = wqc; cc = gc; }
  else if (gc < 1536){ cw = wkc; cc = gc - 768; }
  else { cw = wvc; cc = gc - 1536; }
  float y = 0.f;
  #pragma unroll
  for (int i = 0; i < 4; i++){
    int ts = t - 3 + i;
    if (ts >= 0) y += cw[cc * 4 + i] * qkvg[(size_t)ts * 4608 + gc];
  }
  y = y / (1.f + expf(-y));                     // silu
  if (gc < 1536){                               // l2norm over head (wave-aligned)
    float ss = y * y;
    #pragma unroll
    for (int d = 1; d < 64; d <<= 1) ss += __shfl_xor(ss, d, 64);
    y *= rsqrtf(ss + 1e-6f) * (gc < 768 ? 0.125f : 1.0f);
  }
  if (gc < 768)       qpp[(size_t)t * 768 + gc] = y;
  else if (gc < 1536) kpp[(size_t)t * 768 + gc - 768] = y;
  else                vpp[(size_t)t * 1536 + gc - 1536] = y;
}

// ---------------------------------------------------------------- phase A: per-(head,chunk) WY factors
__global__ __launch_bounds__(256)
void phaseA(const float* __restrict__ qp, const float* __restrict__ kp,
            const float* __restrict__ vp, const float* __restrict__ gkv,
            const float* __restrict__ bev, float* __restrict__ Wt,
            float* __restrict__ Uvv, float* __restrict__ Mg,
            float* __restrict__ Ng, float* __restrict__ Ca,
            float* __restrict__ bv)
{
  const int braw = blockIdx.x;
  const int blk = (braw & 7) * 48 + (braw >> 3);   // 384 % 8 == 0, bijective
  const int h = blk % 12, c = blk / 12, t0 = c * 64;
  const int tid = threadIdx.x;

  __shared__ __align__(16) float Kc[4096];     // K chunk [64][64]
  __shared__ __align__(16) float X[12288];     // [64][192]: cols 0..127 Uv, 128..191 W
  __shared__ float Pp[2016];                   // packed strict-lower P
  __shared__ float gt[64], bb[64], be[64], eg[64];
  __shared__ float Gtot;

  { // load K chunk
    int i = tid >> 2, q4 = tid & 3;
    const float* src = kp + (size_t)(t0 + i) * 768 + h * 64 + q4 * 16;
    #pragma unroll
    for (int e = 0; e < 4; e++)
      *(fx4*)&Kc[i * 64 + q4 * 16 + e * 4] = *(const fx4*)(src + e * 4);
  }
  if (tid < 64){ // within-chunk cumulative log-decay
    float g = gkv[(size_t)(t0 + tid) * 12 + h];
    #pragma unroll
    for (int d = 1; d < 64; d <<= 1){
      float ts = __shfl_up(g, d, 64);
      if (tid >= d) g += ts;
    }
    gt[tid] = g;
    bb[tid] = expf(g);
    be[tid] = bev[(size_t)(t0 + tid) * 12 + h];
    if (tid == 63) Gtot = g;
  }
  __syncthreads();
  const float GT = Gtot;
  if (tid < 64) eg[tid] = expf(GT - gt[tid]);

  { // P_ij = beta_i * (k_i.k_j) * exp(gt_i - gt_j), j < i
    int i = tid >> 2, jb = tid & 3;
    float ki[64];
    #pragma unroll
    for (int d = 0; d < 64; d++) ki[d] = Kc[i * 64 + d];
    float gi = gt[i], bei = be[i];
    int pbase = (i * (i - 1)) >> 1;
    for (int jj = 0; jj < 16; jj++){
      int j = jb * 16 + jj;
      if (j < i){
        float dot = 0.f;
        #pragma unroll
        for (int d = 0; d < 64; d++) dot += ki[d] * Kc[j * 64 + d];
        Pp[pbase + j] = bei * dot * expf(gi - gt[j]);
      }
    }
  }
  { // X init = diag(beta)[V | diag(b)K]
    int i = tid >> 2, seg = tid & 3;
    float bei = be[i], bbi = bb[i];
    #pragma unroll
    for (int u = 0; u < 12; u++){
      int colv = seg * 48 + u * 4;
      fx4 val;
      if (colv < 128){
        val = *(const fx4*)(vp + (size_t)(t0 + i) * 1536 + h * 128 + colv);
        #pragma unroll
        for (int e = 0; e < 4; e++) val[e] *= bei;
      } else {
        int d0 = colv - 128;
        #pragma unroll
        for (int e = 0; e < 4; e++) val[e] = bei * bbi * Kc[i * 64 + d0 + e];
      }
      *(fx4*)&X[i * 192 + colv] = val;
    }
  }
  __syncthreads();

  // forward substitution: X <- (I+P)^-1 X
  for (int i = 1; i < 64; i++){
    if (tid < 192){
      int pbase = (i * (i - 1)) >> 1;
      float accv = 0.f;
      for (int j = 0; j < i; j++) accv += Pp[pbase + j] * X[j * 192 + tid];
      X[i * 192 + tid] -= accv;
    }
    __syncthreads();
  }

  // store Uv, W
  for (int e = tid; e < 12288; e += 256){
    int i = e / 192, colv = e - i * 192;
    float xv = X[e];
    if (colv < 128) Uvv[(size_t)blk * 8192 + i * 128 + colv] = xv;
    else            Wt [(size_t)blk * 4096 + i * 64 + (colv - 128)] = xv;
  }

  { // M = exp(G) I - K'^T W
    int d2 = tid & 63, d1b = tid >> 6;
    for (int ii = 0; ii < 16; ii++){
      int d1 = d1b * 16 + ii;
      float s = 0.f;
      for (int j = 0; j < 64; j++)
        s += eg[j] * Kc[j * 64 + d1] * X[j * 192 + 128 + d2];
      Mg[(size_t)blk * 4096 + d1 * 64 + d2] = ((d1 == d2) ? expf(GT) : 0.f) - s;
    }
  }
  { // N = K'^T Uv
    int vv = tid & 127, d1b = tid >> 7;
    for (int ii = 0; ii < 32; ii++){
      int d1 = d1b * 32 + ii;
      float s = 0.f;
      for (int j = 0; j < 64; j++)
        s += eg[j] * Kc[j * 64 + d1] * X[j * 192 + vv];
      Ng[(size_t)blk * 8192 + d1 * 128 + vv] = s;
    }
  }
  { // Cattn_ij = (q_i.k_j) exp(gt_i-gt_j), j <= i
    int i = tid >> 2, jb = tid & 3;
    float qi[64];
    {
      const float* src = qp + (size_t)(t0 + i) * 768 + h * 64;
      #pragma unroll
      for (int q4 = 0; q4 < 16; q4++){
        fx4 t4 = *(const fx4*)(src + q4 * 4);
        #pragma unroll
        for (int e = 0; e < 4; e++) qi[q4 * 4 + e] = t4[e];
      }
    }
    float gi = gt[i];
    for (int jj = 0; jj < 16; jj++){
      int j = jb * 16 + jj;
      float outv = 0.f;
      if (j <= i){
        float dot = 0.f;
        #pragma unroll
        for (int d = 0; d < 64; d++) dot += qi[d] * Kc[j * 64 + d];
        outv = dot * expf(gi - gt[j]);
      }
      Ca[(size_t)blk * 4096 + i * 64 + j] = outv;
    }
  }
  if (tid < 64) bv[(size_t)blk * 64 + tid] = bb[tid];
}

// ---------------------------------------------------------------- phase B: sequential S <- M S + N
__global__ __launch_bounds__(256)
void phaseB(const float* __restrict__ Mg, const float* __restrict__ Ng,
            float* __restrict__ Sst)
{
  const int h = blockIdx.x >> 2, v0 = (blockIdx.x & 3) * 32;
  const int tid = threadIdx.x, lane = tid & 63, w = tid >> 6;
  const int lm = lane & 15, lg = lane >> 4;
  __shared__ __align__(16) float ST[2048];   // [kb 0..7][vv 0..31][r&7]

  #pragma unroll
  for (int e = 0; e < 2; e++)
    *(fx4*)&ST[(tid + e * 256) * 4] = (fx4){0.f,0.f,0.f,0.f};
  {
    float* dst = Sst + (size_t)h * 8192;     // S_states[0] slice = 0
    #pragma unroll
    for (int e = 0; e < 2; e++){
      int r = (tid >> 3) + e * 32;
      *(fx4*)(dst + (size_t)r * 128 + v0 + (tid & 7) * 4) = (fx4){0.f,0.f,0.f,0.f};
    }
  }
  __syncthreads();

  fx4 rm[2][2];
  float rn[2][4];
  auto loadMN = [&](int cc){
    const float* mb = Mg + ((size_t)cc * 12 + h) * 4096 + (w * 16 + lm) * 64 + lg * 8;
    rm[0][0] = *(const fx4*)(mb);
    rm[0][1] = *(const fx4*)(mb + 4);
    rm[1][0] = *(const fx4*)(mb + 32);
    rm[1][1] = *(const fx4*)(mb + 36);
    const float* nb = Ng + ((size_t)cc * 12 + h) * 8192 + v0;
    #pragma unroll
    for (int nt = 0; nt < 2; nt++)
      #pragma unroll
      for (int j = 0; j < 4; j++)
        rn[nt][j] = nb[(w * 16 + lg * 4 + j) * 128 + nt * 16 + lm];
  };
  loadMN(0);

  for (int c = 0; c < 32; c++){
    hx8 mf[2];
    #pragma unroll
    for (int s = 0; s < 2; s++)
      #pragma unroll
      for (int e = 0; e < 4; e++){
        mf[s][e]     = (_Float16)rm[s][0][e];
        mf[s][4 + e] = (_Float16)rm[s][1][e];
      }
    fx4 acc[2];
    #pragma unroll
    for (int nt = 0; nt < 2; nt++)
      #pragma unroll
      for (int j = 0; j < 4; j++) acc[nt][j] = rn[nt][j];
    if (c + 1 < 32) loadMN(c + 1);

    hx8 bfr[2][2];
    #pragma unroll
    for (int s = 0; s < 2; s++)
      #pragma unroll
      for (int nt = 0; nt < 2; nt++){
        int vv = nt * 16 + lm, kb = s * 4 + lg;
        fx4 p0 = *(const fx4*)&ST[kb * 256 + vv * 8];
        fx4 p1 = *(const fx4*)&ST[kb * 256 + vv * 8 + 4];
        #pragma unroll
        for (int e = 0; e < 4; e++){
          bfr[s][nt][e]     = (_Float16)p0[e];
          bfr[s][nt][4 + e] = (_Float16)p1[e];
        }
      }
    #pragma unroll
    for (int s = 0; s < 2; s++)
      #pragma unroll
      for (int nt = 0; nt < 2; nt++)
        acc[nt] = __builtin_amdgcn_mfma_f32_16x16x32_f16(mf[s], bfr[s][nt], acc[nt], 0, 0, 0);
    __syncthreads();   // all ST reads done
    float* dstS = (c + 1 < 32) ? (Sst + ((size_t)(c + 1) * 12 + h) * 8192 + v0) : nullptr;
    #pragma unroll
    for (int nt = 0; nt < 2; nt++){
      int vv = nt * 16 + lm;
      #pragma unroll
      for (int j = 0; j < 4; j++){
        int r = w * 16 + lg * 4 + j;
        ST[(r >> 3) * 256 + vv * 8 + (r & 7)] = acc[nt][j];
        if (dstS) dstS[(size_t)r * 128 + vv] = acc[nt][j];
      }
    }
    __syncthreads();
  }
}

// ---------------------------------------------------------------- phase C: chunk outputs (XCD-chunk swizzled)
__global__ __launch_bounds__(256)
void phaseC(const float* __restrict__ qp, const float* __restrict__ Sst,
            const float* __restrict__ Wt, const float* __restrict__ Uvv,
            const float* __restrict__ Ca, const float* __restrict__ bv,
            float* __restrict__ oraw)
{
  const int braw = blockIdx.x;
  const int blk = (braw & 7) * 48 + (braw >> 3);   // 384 % 8 == 0, bijective
  const int h = blk % 12, c = blk / 12, t0 = c * 64;
  const int tid = threadIdx.x;

  __shared__ __align__(16) float S0l[8192];
  __shared__ __align__(16) float Ul[8192];
  __shared__ __align__(16) float Wl[4096];
  __shared__ float bl[64];

  #pragma unroll
  for (int e = 0; e < 8; e++){
    int i4 = tid + e * 256;
    *(fx4*)&S0l[i4 * 4] = *(const fx4*)(Sst + (size_t)blk * 8192 + i4 * 4);
    *(fx4*)&Ul[i4 * 4]  = *(const fx4*)(Uvv + (size_t)blk * 8192 + i4 * 4);
  }
  #pragma unroll
  for (int e = 0; e < 4; e++){
    int i4 = tid + e * 256;
    *(fx4*)&Wl[i4 * 4] = *(const fx4*)(Wt + (size_t)blk * 4096 + i4 * 4);
  }
  if (tid < 64) bl[tid] = bv[(size_t)blk * 64 + tid];
  __syncthreads();

  const int v = tid & 127, rh = tid >> 7;
  float s0c[64];
  #pragma unroll
  for (int d = 0; d < 64; d++) s0c[d] = S0l[d * 128 + v];

  // U = Uv - W @ S0
  for (int j = rh * 32; j < rh * 32 + 32; j++){
    float accv = 0.f;
    #pragma unroll
    for (int d = 0; d < 64; d++) accv += Wl[j * 64 + d] * s0c[d];
    Ul[j * 128 + v] -= accv;
  }
  __syncthreads();
  #pragma unroll
  for (int e = 0; e < 4; e++){   // Cattn into Wl
    int i4 = tid + e * 256;
    *(fx4*)&Wl[i4 * 4] = *(const fx4*)(Ca + (size_t)blk * 4096 + i4 * 4);
  }
  __syncthreads();

  // o_i = b_i * q_i S0 + sum_{j<=i} Cattn_ij U_j  (Q direct from global; L2-hot)
  for (int i = rh * 32; i < rh * 32 + 32; i++){
    const float* qi = qp + (size_t)(t0 + i) * 768 + h * 64;
    float aq = 0.f;
    #pragma unroll
    for (int d = 0; d < 64; d++) aq += qi[d] * s0c[d];
    float ao = 0.f;
    for (int j = 0; j <= i; j++) ao += Wl[i * 64 + j] * Ul[j * 128 + v];
    oraw[(size_t)(t0 + i) * 1536 + h * 128 + v] = bl[i] * aq + ao;
  }
}

// ---------------------------------------------------------------- RMSNorm * g_norm_w * silu(g) -> fp16
__global__ __launch_bounds__(256)
void rmsgate(const float* __restrict__ oraw, const float* __restrict__ gx,
             int gstride, const float* __restrict__ gnw, _Float16* __restrict__ ogh)
{
  int t = blockIdx.x, lane = threadIdx.x & 63;
  int h = blockIdx.y * 4 + (threadIdx.x >> 6);
  size_t base = (size_t)t * 1536 + h * 128;
  size_t gbase = (size_t)t * gstride + h * 128;
  float o1 = oraw[base + lane], o2 = oraw[base + 64 + lane];
  float ss = o1 * o1 + o2 * o2;
  #pragma unroll
  for (int d = 1; d < 64; d <<= 1) ss += __shfl_xor(ss, d, 64);
  float r = rsqrtf(ss * (1.f / 128.f) + 1e-5f);
  float g1 = gx[gbase + lane], g2 = gx[gbase + 64 + lane];
  ogh[base + lane]      = (_Float16)(o1 * r * gnw[lane]      * (g1 / (1.f + expf(-g1))));
  ogh[base + 64 + lane] = (_Float16)(o2 * r * gnw[64 + lane] * (g2 / (1.f + expf(-g2))));
}

// ---------------------------------------------------------------- launcher
extern "C" void kernel_launch(void* const* d_in, const int* in_sizes, int n_in,
                              void* d_out, int out_size, void* d_ws, size_t ws_size,
                              hipStream_t stream)
{
  const int*   ids   = (const int*)d_in[0];
  const float* emb   = (const float*)d_in[1];
  const float* Wq    = (const float*)d_in[2];
  const float* Wk    = (const float*)d_in[3];
  const float* Wv    = (const float*)d_in[4];
  const float* Wg    = (const float*)d_in[5];
  const float* wqc   = (const float*)d_in[6];
  const float* wkc   = (const float*)d_in[7];
  const float* wvc   = (const float*)d_in[8];
  const float* Wgk   = (const float*)d_in[9];
  const float* Wb    = (const float*)d_in[10];
  const float* b_b   = (const float*)d_in[11];
  const float* A_log = (const float*)d_in[12];
  const float* dtb   = (const float*)d_in[13];
  const float* gnw   = (const float*)d_in[14];
  const float* Wo    = (const float*)d_in[15];
  const float* Wlm   = (const float*)d_in[16];
  const float* b_lm  = (const float*)d_in[17];
  float* out = (float*)d_out;

  // d_out doubles as scratch for intermediates that die before the LM GEMM.
  float* x    = out;               // 2048x1024 fp32
  float* qkvg = out + 2097152;     // 2048x4608 fp32 [q|k|v|g]
  float* qpp  = out + 11534336;    // 2048x768
  float* kpp  = out + 13107200;    // 2048x768
  float* vpp  = out + 14680064;    // 2048x1536
  float* gkb  = out + 17825792;    // 2048x12
  float* bet  = out + 17850368;    // 2048x12
  float* Wt   = out + 17874944;    // 384x64x64
  float* Uvv  = out + 19447808;    // 384x64x128
  float* Mg   = out + 22593536;    // 384x64x64
  float* Ng   = out + 24166400;    // 384x64x128
  float* Ca   = out + 27312128;    // 384x64x64
  float* bvv  = out + 28884992;    // 384x64
  float* Sst  = out + 28909568;    // 384x64x128 (chunk-start states)
  float* oraw = out + 32055296;    // 2048x1536
  _Float16* x_h  = (_Float16*)(out + 35201024);  // 2048x1024 fp16
  _Float16* og_h = (_Float16*)(out + 36300000);  // 2048x1536 fp16

  // ws layout: h_h | Wqkvg_h | Wo_h | Wlm_h (R5 confirmed ws_size >= 120MB)
  _Float16* h_h     = (_Float16*)d_ws;           // 2048x1024 (survives LM GEMM)
  _Float16* Wqkvg_h = h_h + 2097152;             // 4608x1024 [Wq;Wk;Wv;Wg]
  _Float16* Wo_h    = Wqkvg_h + 4718592;         // 1024x1536
  _Float16* Wlm_h   = Wo_h + 1572864;            // 50257x1024

  cvt16<false><<<384,  256, 0, stream>>>(Wq, Wqkvg_h,           98304);
  cvt16<false><<<384,  256, 0, stream>>>(Wk, Wqkvg_h +  786432, 98304);
  cvt16<false><<<768,  256, 0, stream>>>(Wv, Wqkvg_h + 1572864, 196608);
  cvt16<false><<<768,  256, 0, stream>>>(Wg, Wqkvg_h + 3145728, 196608);
  cvt16<false><<<768,  256, 0, stream>>>(Wo, Wo_h, 196608);
  cvt16<true ><<<2048, 256, 0, stream>>>(Wlm, Wlm_h, 6432896);   // grid-stride

  embed_gkb<<<2048, 256, 0, stream>>>(ids, emb, Wgk, Wb, b_b, A_log, dtb,
                                      x, x_h, gkb, bet);
  gemm_hh<4,2,2,4,false,false><<<dim3(16, 36), 512, 0, stream>>>(x_h, Wqkvg_h, qkvg, nullptr, 2048, 4608, 1024);
  conv_fused<<<dim3(2048, 12), 256, 0, stream>>>(qkvg, wqc, wkc, wvc, qpp, kpp, vpp);
  phaseA<<<384, 256, 0, stream>>>(qpp, kpp, vpp, gkb, bet, Wt, Uvv, Mg, Ng, Ca, bvv);
  phaseB<<<48, 256, 0, stream>>>(Mg, Ng, Sst);
  phaseC<<<384, 256, 0, stream>>>(qpp, Sst, Wt, Uvv, Ca, bvv, oraw);
  rmsgate<<<dim3(2048, 3), 256, 0, stream>>>(oraw, qkvg + 3072, 4608, gnw, og_h);
  gemm_hh<4,2,2,4,true,false><<<dim3(16, 8), 512, 0, stream>>>(og_h, Wo_h, h_h, nullptr, 2048, 1024, 1536);
  // LM head: counted-vmcnt pipeline + LDS-staged coalesced NT epilogue
  gemm_hh<4,2,2,4,false,true><<<dim3(16, 393), 512, 0, stream>>>(h_h, Wlm_h, out, b_lm, 2048, 50257, 1024);
}